// Round 19
// baseline (151.446 us; speedup 1.0000x reference)
//
#include <hip/hip_runtime.h>
#include <hip/hip_bf16.h>
#include <cstdint>

#define NCLOUDS 16
#define N_PER   2048
#define KNN_K   16
#define CAP     48

typedef unsigned long long u64;
typedef __attribute__((ext_vector_type(8))) short bf16x8;
typedef __attribute__((ext_vector_type(4))) float f32x4;
#define INFF __builtin_inff()

// ---- cross-lane xor exchange: DPP for 1/2 (VALU pipe), ds_swizzle for
// 4/8/16 (DS pipe, no addr setup), shfl for 32. All exact xor exchanges. ----
template <int J>
__device__ __forceinline__ int ixor(int x) {
    if constexpr (J == 1)
        return __builtin_amdgcn_update_dpp(0, x, 0xB1, 0xF, 0xF, true);   // quad_perm [1,0,3,2]
    else if constexpr (J == 2)
        return __builtin_amdgcn_update_dpp(0, x, 0x4E, 0xF, 0xF, true);   // quad_perm [2,3,0,1]
    else if constexpr (J <= 16)
        return __builtin_amdgcn_ds_swizzle(x, (J << 10) | 0x1F);          // xor-J bitmode
    else
        return __shfl_xor(x, 32);
}
template <int J> __device__ __forceinline__ float fxor(float x) {
    return __int_as_float(ixor<J>(__float_as_int(x)));
}

// round-to-nearest-even f32 -> bf16 bits (finite inputs only)
__device__ __forceinline__ unsigned short f2bf(float f) {
    const unsigned u = __float_as_uint(f);
    const unsigned r = 0x7fffu + ((u >> 16) & 1u);
    return (unsigned short)((u + r) >> 16);
}

// ---------------------------------------------------------------------------
// KNN v11 = v10 + (a) pass2 dot-form prefilter (exact d2 only for ~1% of
// candidates, exec-masked), (b) select via f32 bitonic on exact d2 + d16
// threshold + ballot slot-write + lowest-index tie fill (output slot ORDER is
// free: downstream max-aggregates; set semantics = top_k tie rule exactly).
// Threshold math unchanged from v7..v10 (passed).
// ---------------------------------------------------------------------------
__global__ __launch_bounds__(512) void knn_kernel(const float* __restrict__ pos,
                                                  int* __restrict__ knn_out,
                                                  const float* __restrict__ W1a,
                                                  const float* __restrict__ b1a,
                                                  float* __restrict__ w1,
                                                  float* __restrict__ v1,
                                                  float* __restrict__ gbuf,
                                                  int* __restrict__ counter)
{
    __shared__ float qshare[3][32];
    __shared__ float smA[4][2][8][16];    // [pair][half][pair-local query][rank]
    __shared__ u64   buf[4][8][CAP];      // [pair][pair-local query][slot]
    __shared__ int   cnt[4][8];

    const int cloud = blockIdx.x >> 6;
    const int qblk  = blockIdx.x & 63;    // 64 qblocks/cloud, 32 queries each
    const int tid   = threadIdx.x;
    const int wave  = tid >> 6;
    const int lane  = tid & 63;
    const int H     = wave & 1;
    const int pr    = wave >> 1;

    const int b0 = cloud * N_PER;

    if (blockIdx.x == 0) {
        if (tid < NCLOUDS * 32) gbuf[tid] = 0.0f;
        if (tid == 0) *counter = 0;
    }

    if (tid < 32) {
        const float* qp = pos + (size_t)(b0 + qblk * 32 + tid) * 3;
        qshare[0][tid] = qp[0];
        qshare[1][tid] = qp[1];
        qshare[2][tid] = qp[2];
        ((int*)cnt)[tid] = 0;
    }

    float cx[16], cy[16], cz[16], sc[16];
#pragma unroll
    for (int jj = 0; jj < 16; ++jj) {
        const int c = H * 1024 + jj * 64 + lane;
        const float* p = pos + (size_t)(b0 + c) * 3;
        cx[jj] = p[0]; cy[jj] = p[1]; cz[jj] = p[2];
        sc[jj] = fmaf(cz[jj], cz[jj], fmaf(cy[jj], cy[jj], cx[jj] * cx[jj]));
    }
    __syncthreads();

    // ================= phase 1: scan + sort lane-minima (ILP-2) ============
#pragma unroll 1
    for (int t = 0; t < 4; ++t) {
        const int qg0 = pr * 8 + 2 * t, qg1 = qg0 + 1;
        const float Q0x = qshare[0][qg0], Q0y = qshare[1][qg0], Q0z = qshare[2][qg0];
        const float Q1x = qshare[0][qg1], Q1y = qshare[1][qg1], Q1z = qshare[2][qg1];
        const float A0x = -2.0f * Q0x, A0y = -2.0f * Q0y, A0z = -2.0f * Q0z;
        const float A1x = -2.0f * Q1x, A1y = -2.0f * Q1y, A1z = -2.0f * Q1z;
        float v0 = INFF, v1r = INFF;
#pragma unroll
        for (int jj = 0; jj < 16; ++jj) {
            float e0 = fmaf(cx[jj], A0x, sc[jj]);
            float e1 = fmaf(cx[jj], A1x, sc[jj]);
            e0 = fmaf(cy[jj], A0y, e0);  e1 = fmaf(cy[jj], A1y, e1);
            e0 = fmaf(cz[jj], A0z, e0);  e1 = fmaf(cz[jj], A1z, e1);
            v0 = fminf(v0, e0);          v1r = fminf(v1r, e1);
        }
#define FS(K, J) { const float o0 = fxor<J>(v0), o1 = fxor<J>(v1r);             \
                   const bool km = (((lane & J) == 0) == ((lane & K) == 0));    \
                   v0 = km ? fminf(v0, o0) : fmaxf(v0, o0);                     \
                   v1r = km ? fminf(v1r, o1) : fmaxf(v1r, o1); }
        FS(2,1)
        FS(4,2) FS(4,1)
        FS(8,4) FS(8,2) FS(8,1)
        FS(16,8) FS(16,4) FS(16,2) FS(16,1)
        FS(32,16) FS(32,8) FS(32,4) FS(32,2) FS(32,1)
        FS(64,32) FS(64,16) FS(64,8) FS(64,4) FS(64,2) FS(64,1)
#undef FS
        if (lane < 16) {
            smA[pr][H][2 * t][lane]     = v0;
            smA[pr][H][2 * t + 1][lane] = v1r;
        }
    }
    __syncthreads();

    // ================= phase 2: merge threshold + collect (ILP-2) ==========
#pragma unroll 1
    for (int t = 0; t < 4; ++t) {
        const int q0 = 2 * t, q1 = q0 + 1;
        float a0 = -INFF, a1 = -INFF, b0v = -INFF, b1v = -INFF;
        if (lane > 0 && lane <= 16) {
            a0 = smA[pr][0][q0][lane - 1];
            a1 = smA[pr][0][q1][lane - 1];
        }
        if (lane < 16) {
            b0v = smA[pr][1][q0][15 - lane];
            b1v = smA[pr][1][q1][15 - lane];
        }
        float m0 = (lane <= 16) ? fmaxf(a0, b0v) : INFF;
        float m1 = (lane <= 16) ? fmaxf(a1, b1v) : INFF;
        m0 = fminf(m0, fxor<1>(m0));   m1 = fminf(m1, fxor<1>(m1));
        m0 = fminf(m0, fxor<2>(m0));   m1 = fminf(m1, fxor<2>(m1));
        m0 = fminf(m0, fxor<4>(m0));   m1 = fminf(m1, fxor<4>(m1));
        m0 = fminf(m0, fxor<8>(m0));   m1 = fminf(m1, fxor<8>(m1));
        m0 = fminf(m0, fxor<16>(m0));  m1 = fminf(m1, fxor<16>(m1));
        m0 = fminf(m0, fxor<32>(m0));  m1 = fminf(m1, fxor<32>(m1));

        const int qg0 = pr * 8 + q0, qg1 = pr * 8 + q1;
        const float Q0x = qshare[0][qg0], Q0y = qshare[1][qg0], Q0z = qshare[2][qg0];
        const float Q1x = qshare[0][qg1], Q1y = qshare[1][qg1], Q1z = qshare[2][qg1];
        const float A0x = -2.0f * Q0x, A0y = -2.0f * Q0y, A0z = -2.0f * Q0z;
        const float A1x = -2.0f * Q1x, A1y = -2.0f * Q1y, A1z = -2.0f * Q1z;
        const float qq0 = fmaf(Q0z, Q0z, fmaf(Q0y, Q0y, Q0x * Q0x));
        const float qq1 = fmaf(Q1z, Q1z, fmaf(Q1y, Q1y, Q1x * Q1x));
        const float T0 = (m0 + qq0) * (1.0f + 1e-5f) + 1e-4f;
        const float T1 = (m1 + qq1) * (1.0f + 1e-5f) + 1e-4f;
        const float F0 = T0 + 1e-4f;   // prefilter margin (covers e+qq vs d2 rounding)
        const float F1 = T1 + 1e-4f;

#pragma unroll
        for (int jj = 0; jj < 16; ++jj) {
            const int c = H * 1024 + jj * 64 + lane;
            // cheap dot-form prefilter (3 fma + add + cmp); exact d2 only inside
            float e0 = fmaf(cx[jj], A0x, sc[jj]);
            e0 = fmaf(cy[jj], A0y, e0);
            e0 = fmaf(cz[jj], A0z, e0);
            if (e0 + qq0 <= F0) {
                const float dx0 = __fsub_rn(Q0x, cx[jj]);
                const float dy0 = __fsub_rn(Q0y, cy[jj]);
                const float dz0 = __fsub_rn(Q0z, cz[jj]);
                const float d20 = __fadd_rn(__fadd_rn(__fmul_rn(dx0, dx0), __fmul_rn(dy0, dy0)),
                                            __fmul_rn(dz0, dz0));
                if (d20 <= T0) {
                    const int slot = atomicAdd(&cnt[pr][q0], 1);
                    if (slot < CAP)
                        buf[pr][q0][slot] = ((u64)__float_as_uint(d20) << 32) | (unsigned)c;
                }
            }
            float e1 = fmaf(cx[jj], A1x, sc[jj]);
            e1 = fmaf(cy[jj], A1y, e1);
            e1 = fmaf(cz[jj], A1z, e1);
            if (e1 + qq1 <= F1) {
                const float dx1 = __fsub_rn(Q1x, cx[jj]);
                const float dy1 = __fsub_rn(Q1y, cy[jj]);
                const float dz1 = __fsub_rn(Q1z, cz[jj]);
                const float d21 = __fadd_rn(__fadd_rn(__fmul_rn(dx1, dx1), __fmul_rn(dy1, dy1)),
                                            __fmul_rn(dz1, dz1));
                if (d21 <= T1) {
                    const int slot = atomicAdd(&cnt[pr][q1], 1);
                    if (slot < CAP)
                        buf[pr][q1][slot] = ((u64)__float_as_uint(d21) << 32) | (unsigned)c;
                }
            }
        }
    }
    __syncthreads();

    // ========== phase 3: select top-16 set (f32 sort + d16 + ballot) =======
#pragma unroll 1
    for (int s = 0; s < 2; ++s) {
        const int q0 = H * 4 + 2 * s, q1 = q0 + 1;
        const int n0 = min(cnt[pr][q0], CAP);
        const int n1 = min(cnt[pr][q1], CAP);
        float d0 = INFF, d1 = INFF;
        int   i0 = 0x7fffffff, i1 = 0x7fffffff;
        if (lane < n0) {
            const u64 kk = buf[pr][q0][lane];
            d0 = __uint_as_float((unsigned)(kk >> 32));
            i0 = (int)(unsigned)(kk & 0xffffffffu);
        }
        if (lane < n1) {
            const u64 kk = buf[pr][q1][lane];
            d1 = __uint_as_float((unsigned)(kk >> 32));
            i1 = (int)(unsigned)(kk & 0xffffffffu);
        }
        // ascending f32 bitonic on values (exact d2) to locate the 16th
        float a0 = d0, a1 = d1;
#define FS(K, J) { const float o0 = fxor<J>(a0), o1 = fxor<J>(a1);              \
                   const bool km = (((lane & J) == 0) == ((lane & K) == 0));    \
                   a0 = km ? fminf(a0, o0) : fmaxf(a0, o0);                     \
                   a1 = km ? fminf(a1, o1) : fmaxf(a1, o1); }
        FS(2,1)
        FS(4,2) FS(4,1)
        FS(8,4) FS(8,2) FS(8,1)
        FS(16,8) FS(16,4) FS(16,2) FS(16,1)
        FS(32,16) FS(32,8) FS(32,4) FS(32,2) FS(32,1)
        FS(64,32) FS(64,16) FS(64,8) FS(64,4) FS(64,2) FS(64,1)
#undef FS
        const float d16_0 = __shfl(a0, KNN_K - 1);
        const float d16_1 = __shfl(a1, KNN_K - 1);

        int* outp0 = knn_out + ((size_t)b0 + qblk * 32 + pr * 8 + q0) * KNN_K;
        int* outp1 = knn_out + ((size_t)b0 + qblk * 32 + pr * 8 + q1) * KNN_K;
        const u64 lmask = (1ull << lane) - 1;

        const u64 blt0 = __ballot(d0 < d16_0);
        const u64 blt1 = __ballot(d1 < d16_1);
        if (d0 < d16_0) outp0[__popcll(blt0 & lmask)] = b0 + i0;
        if (d1 < d16_1) outp1[__popcll(blt1 & lmask)] = b0 + i1;
        const int c10 = (int)__popcll(blt0);
        const int c11 = (int)__popcll(blt1);
        u64 beq0 = __ballot(d0 == d16_0);
        u64 beq1 = __ballot(d1 == d16_1);
        // fill remaining slots with lowest-index ties (top_k tie rule)
#pragma unroll 1
        for (int it = c10; it < KNN_K; ++it) {
            int cand = ((beq0 >> lane) & 1) ? i0 : 0x7fffffff;
            cand = min(cand, ixor<1>(cand));
            cand = min(cand, ixor<2>(cand));
            cand = min(cand, ixor<4>(cand));
            cand = min(cand, ixor<8>(cand));
            cand = min(cand, ixor<16>(cand));
            cand = min(cand, ixor<32>(cand));
            const bool own = ((beq0 >> lane) & 1) && (i0 == cand);
            if (own) outp0[it] = b0 + i0;
            beq0 &= ~__ballot(own);
        }
#pragma unroll 1
        for (int it = c11; it < KNN_K; ++it) {
            int cand = ((beq1 >> lane) & 1) ? i1 : 0x7fffffff;
            cand = min(cand, ixor<1>(cand));
            cand = min(cand, ixor<2>(cand));
            cand = min(cand, ixor<4>(cand));
            cand = min(cand, ixor<8>(cand));
            cand = min(cand, ixor<16>(cand));
            cand = min(cand, ixor<32>(cand));
            const bool own = ((beq1 >> lane) & 1) && (i1 == cand);
            if (own) outp1[it] = b0 + i1;
            beq1 &= ~__ballot(own);
        }
    }

    // ================= fused pre1 epilogue (this block's 32 points) ========
    {
        const int pt = tid >> 4;            // 0..31
        const int kk = tid & 15;
        const int gp = b0 + qblk * 32 + pt;
        const float p0 = pos[3 * (size_t)gp + 0];
        const float p1 = pos[3 * (size_t)gp + 1];
        const float p2 = pos[3 * (size_t)gp + 2];
        float vA = 0.f, vB = 0.f;
        float wA = b1a[kk], wB = b1a[16 + kk];
#pragma unroll
        for (int d = 0; d < 3; ++d) {
            const float pd = d == 0 ? p0 : (d == 1 ? p1 : p2);
            wA = fmaf(pd, W1a[d * 32 + kk],        wA);
            wB = fmaf(pd, W1a[d * 32 + 16 + kk],   wB);
            vA = fmaf(pd, W1a[(3 + d) * 32 + kk],      vA);
            vB = fmaf(pd, W1a[(3 + d) * 32 + 16 + kk], vB);
        }
        w1[(size_t)gp * 32 + kk]      = wA + vA;
        w1[(size_t)gp * 32 + 16 + kk] = wB + vB;
        v1[(size_t)gp * 32 + kk]      = vA;
        v1[(size_t)gp * 32 + 16 + kk] = vB;
    }
}

// ---------------------------------------------------------------------------
// Edge-MLP layer via MFMA (R18, passed). Wave = 64 edges = 4 points x 16
// neighbors; hid f32 -> bf16 LDS rows -> A-frag ds_read; B = Wb bf16 tiles;
// 2x mfma_f32_16x16x32_bf16; D col=lane&15 row=(lane>>4)*4+reg; max over 16
// edge-rows = 3 reg-max + xor16/32; +bias, relu. XCD swizzle clusters each
// cloud's blocks on one XCD (R16: L2-locality win).
// MODE 1: + pre2 epilogue. MODE 2: + fused pool/classifier.
// ---------------------------------------------------------------------------
template <int MODE>
__global__ __launch_bounds__(256) void layer_kernel(
    const int*   __restrict__ knn,
    const float* __restrict__ Wb, const float* __restrict__ bb,
    const float* __restrict__ w,  const float* __restrict__ v,
    const float* __restrict__ pos,
    const float* __restrict__ Wna, const float* __restrict__ bna,
    float* __restrict__ outA, float* __restrict__ outB,
    const float* __restrict__ Wc, const float* __restrict__ bc,
    float* __restrict__ gbuf, int* __restrict__ counter,
    float* __restrict__ out)
{
    __shared__ uint4 hidp[4][64][5];   // [wave][edge][4 used + 1 pad] = 20KB
    __shared__ float hs[16][32];
    __shared__ float gl[NCLOUDS * 32];
    __shared__ int   lastFlag;

    const int tid  = threadIdx.x;
    const int wv   = tid >> 6;
    const int lane = tid & 63;
    // XCD-aware swizzle: cluster each cloud's blocks on one XCD
    const int xcd   = blockIdx.x & 7;
    const int tt    = blockIdx.x >> 3;
    const int cloud = xcd * 2 + (tt & 1);
    const int ib    = tt >> 1;                  // 0..127 within cloud
    const int P0    = cloud * N_PER + ib * 16;  // first point of block
    const int k     = tid & 15;
    const int pl    = tid >> 4;
    const int p     = P0 + pl;                  // this lane's point
    const int j     = knn[(size_t)p * KNN_K + k];

    const float4* w4 = (const float4*)w;
    const float4* v4 = (const float4*)v;

    float hid[32];
#pragma unroll
    for (int i = 0; i < 8; ++i) {
        const float4 a = w4[(size_t)j * 8 + i];
        const float4 b = v4[(size_t)p * 8 + i];
        hid[4 * i + 0] = fmaxf(a.x - b.x, 0.0f);
        hid[4 * i + 1] = fmaxf(a.y - b.y, 0.0f);
        hid[4 * i + 2] = fmaxf(a.z - b.z, 0.0f);
        hid[4 * i + 3] = fmaxf(a.w - b.w, 0.0f);
    }

    // ---- B fragments: Wb bf16, tile n: col = n*16 + (lane&15), k chunk ----
    const int kg = (lane >> 4) * 8;
    const int cl = lane & 15;
    bf16x8 bfr[2];
#pragma unroll
    for (int n = 0; n < 2; ++n)
#pragma unroll
        for (int jj = 0; jj < 8; ++jj)
            bfr[n][jj] = (short)f2bf(Wb[(kg + jj) * 32 + n * 16 + cl]);

    // ---- pack hid -> bf16 pairs -> LDS row (own edge = own lane) ----
    {
        uint4 pk[4];
#pragma unroll
        for (int q4 = 0; q4 < 4; ++q4) {
            unsigned a0 = (unsigned)f2bf(hid[8 * q4 + 0]) | ((unsigned)f2bf(hid[8 * q4 + 1]) << 16);
            unsigned a1 = (unsigned)f2bf(hid[8 * q4 + 2]) | ((unsigned)f2bf(hid[8 * q4 + 3]) << 16);
            unsigned a2 = (unsigned)f2bf(hid[8 * q4 + 4]) | ((unsigned)f2bf(hid[8 * q4 + 5]) << 16);
            unsigned a3 = (unsigned)f2bf(hid[8 * q4 + 6]) | ((unsigned)f2bf(hid[8 * q4 + 7]) << 16);
            pk[q4] = make_uint4(a0, a1, a2, a3);
        }
#pragma unroll
        for (int q4 = 0; q4 < 4; ++q4) hidp[wv][lane][q4] = pk[q4];
    }
    // same-wave LDS write->read: compiler inserts the lgkmcnt hazard waits

    const f32x4 zero = {0.f, 0.f, 0.f, 0.f};
#pragma unroll
    for (int m = 0; m < 4; ++m) {
        const uint4 av = hidp[wv][m * 16 + cl][lane >> 4];
        const bf16x8 afr = __builtin_bit_cast(bf16x8, av);
        const f32x4 d0 = __builtin_amdgcn_mfma_f32_16x16x32_bf16(afr, bfr[0], zero, 0, 0, 0);
        const f32x4 d1 = __builtin_amdgcn_mfma_f32_16x16x32_bf16(afr, bfr[1], zero, 0, 0, 0);
        float m0 = fmaxf(fmaxf(d0[0], d0[1]), fmaxf(d0[2], d0[3]));
        float m1 = fmaxf(fmaxf(d1[0], d1[1]), fmaxf(d1[2], d1[3]));
        m0 = fmaxf(m0, fxor<16>(m0));  m1 = fmaxf(m1, fxor<16>(m1));
        m0 = fmaxf(m0, fxor<32>(m0));  m1 = fmaxf(m1, fxor<32>(m1));
        const int bp = wv * 4 + m;
        hs[bp][cl]      = fmaxf(bb[cl]      + m0, 0.0f);   // outer relu
        hs[bp][16 + cl] = fmaxf(bb[16 + cl] + m1, 0.0f);
    }
    __syncthreads();

    if constexpr (MODE == 1) {
        // pre2: thread (pl,k) computes channels k and k+16 of w2,v2
        float accA = bna[k], accB = bna[16 + k];
#pragma unroll
        for (int c = 0; c < 32; ++c) {
            const float hc = hs[pl][c];
            accA = fmaf(hc, Wna[c * 32 + k],      accA);
            accB = fmaf(hc, Wna[c * 32 + 16 + k], accB);
        }
        float vA = 0.f, vB = 0.f;
#pragma unroll
        for (int d = 0; d < 3; ++d) {
            const float pd = pos[3 * (size_t)p + d];
            vA = fmaf(pd, Wna[(32 + d) * 32 + k],      vA);
            vB = fmaf(pd, Wna[(32 + d) * 32 + 16 + k], vB);
        }
        outA[(size_t)p * 32 + k]      = accA + vA;
        outA[(size_t)p * 32 + 16 + k] = accB + vB;
        outB[(size_t)p * 32 + k]      = vA;
        outB[(size_t)p * 32 + 16 + k] = vB;
    } else {
        // fused pool: block-local max over 16 points, then device atomicMax
        if (tid < 32) {
            float m = hs[0][tid];
#pragma unroll
            for (int p2 = 1; p2 < 16; ++p2) m = fmaxf(m, hs[p2][tid]);
            atomicMax((int*)&gbuf[cloud * 32 + tid], __float_as_int(m));
        }
        __syncthreads();
        if (tid == 0) {
            __threadfence();
            lastFlag = (atomicAdd(counter, 1) == (int)gridDim.x - 1);
        }
        __syncthreads();
        if (lastFlag) {
            for (int t = tid; t < NCLOUDS * 32; t += 256)
                gl[t] = __int_as_float(atomicMax((int*)&gbuf[t], 0)); // coherent read
            __syncthreads();
            if (tid < NCLOUDS * 10) {
                const int cl2 = tid / 10, cls = tid - cl2 * 10;
                float s2 = bc[cls];
#pragma unroll
                for (int c = 0; c < 32; ++c)
                    s2 = fmaf(gl[cl2 * 32 + c], Wc[c * 10 + cls], s2);
                out[tid] = s2;
            }
        }
    }
}

extern "C" void kernel_launch(void* const* d_in, const int* in_sizes, int n_in,
                              void* d_out, int out_size, void* d_ws, size_t ws_size,
                              hipStream_t stream)
{
    const float* pos = (const float*)d_in[0];
    const float* W1a = (const float*)d_in[2];
    const float* b1a = (const float*)d_in[3];
    const float* W1b = (const float*)d_in[4];
    const float* b1b = (const float*)d_in[5];
    const float* W2a = (const float*)d_in[6];
    const float* b2a = (const float*)d_in[7];
    const float* W2b = (const float*)d_in[8];
    const float* b2b = (const float*)d_in[9];
    const float* Wc  = (const float*)d_in[10];
    const float* bc  = (const float*)d_in[11];

    int*   knn     = (int*)d_ws;                                   // 2 MB
    float* w1      = (float*)((char*)d_ws + (size_t)(2  << 20));   // 4 MB
    float* v1      = (float*)((char*)d_ws + (size_t)(6  << 20));   // 4 MB
    float* w2      = (float*)((char*)d_ws + (size_t)(10 << 20));   // 4 MB
    float* v2      = (float*)((char*)d_ws + (size_t)(14 << 20));   // 4 MB
    float* gbuf    = (float*)((char*)d_ws + (size_t)(18 << 20));   // 2 KB
    int*   counter = (int*)((char*)d_ws + (size_t)(18 << 20) + 4096);
    float* out     = (float*)d_out;

    const int npts = NCLOUDS * N_PER;

    knn_kernel<<<dim3(NCLOUDS * 64), dim3(512), 0, stream>>>(
        pos, knn, W1a, b1a, w1, v1, gbuf, counter);
    layer_kernel<1><<<dim3(npts * KNN_K / 256), dim3(256), 0, stream>>>(
        knn, W1b, b1b, w1, v1, pos, W2a, b2a, w2, v2,
        nullptr, nullptr, nullptr, nullptr, nullptr);
    layer_kernel<2><<<dim3(npts * KNN_K / 256), dim3(256), 0, stream>>>(
        knn, W2b, b2b, w2, v2, pos, nullptr, nullptr, nullptr, nullptr,
        Wc, bc, gbuf, counter, out);
}

// Round 20
// 122.594 us; speedup vs baseline: 1.2354x; 1.2354x over previous
//
#include <hip/hip_runtime.h>
#include <hip/hip_bf16.h>
#include <cstdint>

#define NCLOUDS 16
#define N_PER   2048
#define KNN_K   16
#define CAP     48

typedef unsigned long long u64;
typedef __attribute__((ext_vector_type(8))) short bf16x8;
typedef __attribute__((ext_vector_type(4))) float f32x4;
#define INFF __builtin_inff()

// ---- cross-lane xor exchange: DPP for 1/2 (VALU pipe), ds_swizzle for
// 4/8/16 (DS pipe, no addr setup), shfl for 32. All exact xor exchanges. ----
template <int J>
__device__ __forceinline__ int ixor(int x) {
    if constexpr (J == 1)
        return __builtin_amdgcn_update_dpp(0, x, 0xB1, 0xF, 0xF, true);   // quad_perm [1,0,3,2]
    else if constexpr (J == 2)
        return __builtin_amdgcn_update_dpp(0, x, 0x4E, 0xF, 0xF, true);   // quad_perm [2,3,0,1]
    else if constexpr (J <= 16)
        return __builtin_amdgcn_ds_swizzle(x, (J << 10) | 0x1F);          // xor-J bitmode
    else
        return __shfl_xor(x, 32);
}
template <int J> __device__ __forceinline__ float fxor(float x) {
    return __int_as_float(ixor<J>(__float_as_int(x)));
}
template <int J> __device__ __forceinline__ u64 uxor(u64 x) {
    const int lo = ixor<J>((int)(x & 0xffffffffULL));
    const int hi = ixor<J>((int)(x >> 32));
    return ((u64)(unsigned)hi << 32) | (unsigned)lo;
}

// round-to-nearest-even f32 -> bf16 bits (finite inputs only)
__device__ __forceinline__ unsigned short f2bf(float f) {
    const unsigned u = __float_as_uint(f);
    const unsigned r = 0x7fffu + ((u >> 16) & 1u);
    return (unsigned short)((u + r) >> 16);
}

// ---------------------------------------------------------------------------
// KNN (R18 version, passed @57.6us — R19's prefilter+ballot-select pushed
// VGPR 60->84, occupancy 4->3 blocks/CU, knn +28us; reverted. knn is
// occupancy-dominated: 64-VGPR is the cliff edge).
// v10 math: wave pairs, 16 cands/lane in regs, dot-form pass1 minima,
// per-wave sorted-16, union-16th merge threshold (+rounding margin),
// exact-d2 collect, u64 bitonic select with top_k tie order.
// + fused pre1 epilogue; zeroes gbuf + counter each call (graph-replay safe).
// ---------------------------------------------------------------------------
__global__ __launch_bounds__(512) void knn_kernel(const float* __restrict__ pos,
                                                  int* __restrict__ knn_out,
                                                  const float* __restrict__ W1a,
                                                  const float* __restrict__ b1a,
                                                  float* __restrict__ w1,
                                                  float* __restrict__ v1,
                                                  float* __restrict__ gbuf,
                                                  int* __restrict__ counter)
{
    __shared__ float qshare[3][32];
    __shared__ float smA[4][2][8][16];    // [pair][half][pair-local query][rank]
    __shared__ u64   buf[4][8][CAP];      // [pair][pair-local query][slot]
    __shared__ int   cnt[4][8];

    const int cloud = blockIdx.x >> 6;
    const int qblk  = blockIdx.x & 63;    // 64 qblocks/cloud, 32 queries each
    const int tid   = threadIdx.x;
    const int wave  = tid >> 6;
    const int lane  = tid & 63;
    const int H     = wave & 1;
    const int pr    = wave >> 1;

    const int b0 = cloud * N_PER;

    if (blockIdx.x == 0) {
        if (tid < NCLOUDS * 32) gbuf[tid] = 0.0f;
        if (tid == 0) *counter = 0;
    }

    if (tid < 32) {
        const float* qp = pos + (size_t)(b0 + qblk * 32 + tid) * 3;
        qshare[0][tid] = qp[0];
        qshare[1][tid] = qp[1];
        qshare[2][tid] = qp[2];
        ((int*)cnt)[tid] = 0;
    }

    float cx[16], cy[16], cz[16], sc[16];
#pragma unroll
    for (int jj = 0; jj < 16; ++jj) {
        const int c = H * 1024 + jj * 64 + lane;
        const float* p = pos + (size_t)(b0 + c) * 3;
        cx[jj] = p[0]; cy[jj] = p[1]; cz[jj] = p[2];
        sc[jj] = fmaf(cz[jj], cz[jj], fmaf(cy[jj], cy[jj], cx[jj] * cx[jj]));
    }
    __syncthreads();

    // ================= phase 1: scan + sort lane-minima (ILP-2) ============
#pragma unroll 1
    for (int t = 0; t < 4; ++t) {
        const int qg0 = pr * 8 + 2 * t, qg1 = qg0 + 1;
        const float Q0x = qshare[0][qg0], Q0y = qshare[1][qg0], Q0z = qshare[2][qg0];
        const float Q1x = qshare[0][qg1], Q1y = qshare[1][qg1], Q1z = qshare[2][qg1];
        const float A0x = -2.0f * Q0x, A0y = -2.0f * Q0y, A0z = -2.0f * Q0z;
        const float A1x = -2.0f * Q1x, A1y = -2.0f * Q1y, A1z = -2.0f * Q1z;
        float v0 = INFF, v1r = INFF;
#pragma unroll
        for (int jj = 0; jj < 16; ++jj) {
            float e0 = fmaf(cx[jj], A0x, sc[jj]);
            float e1 = fmaf(cx[jj], A1x, sc[jj]);
            e0 = fmaf(cy[jj], A0y, e0);  e1 = fmaf(cy[jj], A1y, e1);
            e0 = fmaf(cz[jj], A0z, e0);  e1 = fmaf(cz[jj], A1z, e1);
            v0 = fminf(v0, e0);          v1r = fminf(v1r, e1);
        }
#define FS(K, J) { const float o0 = fxor<J>(v0), o1 = fxor<J>(v1r);             \
                   const bool km = (((lane & J) == 0) == ((lane & K) == 0));    \
                   v0 = km ? fminf(v0, o0) : fmaxf(v0, o0);                     \
                   v1r = km ? fminf(v1r, o1) : fmaxf(v1r, o1); }
        FS(2,1)
        FS(4,2) FS(4,1)
        FS(8,4) FS(8,2) FS(8,1)
        FS(16,8) FS(16,4) FS(16,2) FS(16,1)
        FS(32,16) FS(32,8) FS(32,4) FS(32,2) FS(32,1)
        FS(64,32) FS(64,16) FS(64,8) FS(64,4) FS(64,2) FS(64,1)
#undef FS
        if (lane < 16) {
            smA[pr][H][2 * t][lane]     = v0;
            smA[pr][H][2 * t + 1][lane] = v1r;
        }
    }
    __syncthreads();

    // ================= phase 2: merge threshold + collect (ILP-2) ==========
#pragma unroll 1
    for (int t = 0; t < 4; ++t) {
        const int q0 = 2 * t, q1 = q0 + 1;
        float a0 = -INFF, a1 = -INFF, b0v = -INFF, b1v = -INFF;
        if (lane > 0 && lane <= 16) {
            a0 = smA[pr][0][q0][lane - 1];
            a1 = smA[pr][0][q1][lane - 1];
        }
        if (lane < 16) {
            b0v = smA[pr][1][q0][15 - lane];
            b1v = smA[pr][1][q1][15 - lane];
        }
        float m0 = (lane <= 16) ? fmaxf(a0, b0v) : INFF;
        float m1 = (lane <= 16) ? fmaxf(a1, b1v) : INFF;
        m0 = fminf(m0, fxor<1>(m0));   m1 = fminf(m1, fxor<1>(m1));
        m0 = fminf(m0, fxor<2>(m0));   m1 = fminf(m1, fxor<2>(m1));
        m0 = fminf(m0, fxor<4>(m0));   m1 = fminf(m1, fxor<4>(m1));
        m0 = fminf(m0, fxor<8>(m0));   m1 = fminf(m1, fxor<8>(m1));
        m0 = fminf(m0, fxor<16>(m0));  m1 = fminf(m1, fxor<16>(m1));
        m0 = fminf(m0, fxor<32>(m0));  m1 = fminf(m1, fxor<32>(m1));

        const int qg0 = pr * 8 + q0, qg1 = pr * 8 + q1;
        const float Q0x = qshare[0][qg0], Q0y = qshare[1][qg0], Q0z = qshare[2][qg0];
        const float Q1x = qshare[0][qg1], Q1y = qshare[1][qg1], Q1z = qshare[2][qg1];
        const float qq0 = fmaf(Q0z, Q0z, fmaf(Q0y, Q0y, Q0x * Q0x));
        const float qq1 = fmaf(Q1z, Q1z, fmaf(Q1y, Q1y, Q1x * Q1x));
        const float T0 = (m0 + qq0) * (1.0f + 1e-5f) + 1e-4f;
        const float T1 = (m1 + qq1) * (1.0f + 1e-5f) + 1e-4f;

#pragma unroll
        for (int jj = 0; jj < 16; ++jj) {
            const int c = H * 1024 + jj * 64 + lane;
            const float dx0 = __fsub_rn(Q0x, cx[jj]);
            const float dy0 = __fsub_rn(Q0y, cy[jj]);
            const float dz0 = __fsub_rn(Q0z, cz[jj]);
            const float d20 = __fadd_rn(__fadd_rn(__fmul_rn(dx0, dx0), __fmul_rn(dy0, dy0)),
                                        __fmul_rn(dz0, dz0));
            if (d20 <= T0) {
                const int slot = atomicAdd(&cnt[pr][q0], 1);
                if (slot < CAP)
                    buf[pr][q0][slot] = ((u64)__float_as_uint(d20) << 32) | (unsigned)c;
            }
            const float dx1 = __fsub_rn(Q1x, cx[jj]);
            const float dy1 = __fsub_rn(Q1y, cy[jj]);
            const float dz1 = __fsub_rn(Q1z, cz[jj]);
            const float d21 = __fadd_rn(__fadd_rn(__fmul_rn(dx1, dx1), __fmul_rn(dy1, dy1)),
                                        __fmul_rn(dz1, dz1));
            if (d21 <= T1) {
                const int slot = atomicAdd(&cnt[pr][q1], 1);
                if (slot < CAP)
                    buf[pr][q1][slot] = ((u64)__float_as_uint(d21) << 32) | (unsigned)c;
            }
        }
    }
    __syncthreads();

    // ================= phase 3: select top-16 (ILP-2, 2 iters/wave) ========
#pragma unroll 1
    for (int s = 0; s < 2; ++s) {
        const int q0 = H * 4 + 2 * s, q1 = q0 + 1;
        const int n0 = min(cnt[pr][q0], CAP);
        const int n1 = min(cnt[pr][q1], CAP);
        u64 k0 = (lane < n0) ? buf[pr][q0][lane] : ~0ULL;
        u64 k1 = (lane < n1) ? buf[pr][q1][lane] : ~0ULL;
#define US(K, J) { const u64 o0 = uxor<J>(k0), o1 = uxor<J>(k1);                \
                   const bool km = (((lane & J) == 0) == ((lane & K) == 0));    \
                   const u64 l0 = k0 < o0 ? k0 : o0, h0 = k0 < o0 ? o0 : k0;    \
                   k0 = km ? l0 : h0;                                           \
                   const u64 l1 = k1 < o1 ? k1 : o1, h1 = k1 < o1 ? o1 : k1;    \
                   k1 = km ? l1 : h1; }
        US(2,1)
        US(4,2) US(4,1)
        US(8,4) US(8,2) US(8,1)
        US(16,8) US(16,4) US(16,2) US(16,1)
        US(32,16) US(32,8) US(32,4) US(32,2) US(32,1)
        US(64,32) US(64,16) US(64,8) US(64,4) US(64,2) US(64,1)
#undef US
        if (lane < KNN_K) {
            knn_out[((size_t)b0 + qblk * 32 + pr * 8 + q0) * KNN_K + lane] =
                b0 + (int)(unsigned)(k0 & 0xffffffffu);
            knn_out[((size_t)b0 + qblk * 32 + pr * 8 + q1) * KNN_K + lane] =
                b0 + (int)(unsigned)(k1 & 0xffffffffu);
        }
    }

    // ================= fused pre1 epilogue (this block's 32 points) ========
    {
        const int pt = tid >> 4;            // 0..31
        const int kk = tid & 15;
        const int gp = b0 + qblk * 32 + pt;
        const float p0 = pos[3 * (size_t)gp + 0];
        const float p1 = pos[3 * (size_t)gp + 1];
        const float p2 = pos[3 * (size_t)gp + 2];
        float vA = 0.f, vB = 0.f;
        float wA = b1a[kk], wB = b1a[16 + kk];
#pragma unroll
        for (int d = 0; d < 3; ++d) {
            const float pd = d == 0 ? p0 : (d == 1 ? p1 : p2);
            wA = fmaf(pd, W1a[d * 32 + kk],        wA);
            wB = fmaf(pd, W1a[d * 32 + 16 + kk],   wB);
            vA = fmaf(pd, W1a[(3 + d) * 32 + kk],      vA);
            vB = fmaf(pd, W1a[(3 + d) * 32 + 16 + kk], vB);
        }
        w1[(size_t)gp * 32 + kk]      = wA + vA;
        w1[(size_t)gp * 32 + 16 + kk] = wB + vB;
        v1[(size_t)gp * 32 + kk]      = vA;
        v1[(size_t)gp * 32 + 16 + kk] = vB;
    }
}

// ---------------------------------------------------------------------------
// Edge-MLP layer via MFMA (R18, passed). Wave = 64 edges = 4 points x 16
// neighbors; hid f32 -> bf16 LDS rows -> A-frag ds_read; B = Wb bf16 tiles;
// 2x mfma_f32_16x16x32_bf16; D col=lane&15 row=(lane>>4)*4+reg; max over 16
// edge-rows = 3 reg-max + xor16/32; +bias, relu. XCD swizzle clusters each
// cloud's blocks on one XCD (R16: L2-locality win).
// MODE 1: + pre2 epilogue. MODE 2: + fused pool/classifier.
// ---------------------------------------------------------------------------
template <int MODE>
__global__ __launch_bounds__(256) void layer_kernel(
    const int*   __restrict__ knn,
    const float* __restrict__ Wb, const float* __restrict__ bb,
    const float* __restrict__ w,  const float* __restrict__ v,
    const float* __restrict__ pos,
    const float* __restrict__ Wna, const float* __restrict__ bna,
    float* __restrict__ outA, float* __restrict__ outB,
    const float* __restrict__ Wc, const float* __restrict__ bc,
    float* __restrict__ gbuf, int* __restrict__ counter,
    float* __restrict__ out)
{
    __shared__ uint4 hidp[4][64][5];   // [wave][edge][4 used + 1 pad] = 20KB
    __shared__ float hs[16][32];
    __shared__ float gl[NCLOUDS * 32];
    __shared__ int   lastFlag;

    const int tid  = threadIdx.x;
    const int wv   = tid >> 6;
    const int lane = tid & 63;
    // XCD-aware swizzle: cluster each cloud's blocks on one XCD
    const int xcd   = blockIdx.x & 7;
    const int tt    = blockIdx.x >> 3;
    const int cloud = xcd * 2 + (tt & 1);
    const int ib    = tt >> 1;                  // 0..127 within cloud
    const int P0    = cloud * N_PER + ib * 16;  // first point of block
    const int k     = tid & 15;
    const int pl    = tid >> 4;
    const int p     = P0 + pl;                  // this lane's point
    const int j     = knn[(size_t)p * KNN_K + k];

    const float4* w4 = (const float4*)w;
    const float4* v4 = (const float4*)v;

    float hid[32];
#pragma unroll
    for (int i = 0; i < 8; ++i) {
        const float4 a = w4[(size_t)j * 8 + i];
        const float4 b = v4[(size_t)p * 8 + i];
        hid[4 * i + 0] = fmaxf(a.x - b.x, 0.0f);
        hid[4 * i + 1] = fmaxf(a.y - b.y, 0.0f);
        hid[4 * i + 2] = fmaxf(a.z - b.z, 0.0f);
        hid[4 * i + 3] = fmaxf(a.w - b.w, 0.0f);
    }

    // ---- B fragments: Wb bf16, tile n: col = n*16 + (lane&15), k chunk ----
    const int kg = (lane >> 4) * 8;
    const int cl = lane & 15;
    bf16x8 bfr[2];
#pragma unroll
    for (int n = 0; n < 2; ++n)
#pragma unroll
        for (int jj = 0; jj < 8; ++jj)
            bfr[n][jj] = (short)f2bf(Wb[(kg + jj) * 32 + n * 16 + cl]);

    // ---- pack hid -> bf16 pairs -> LDS row (own edge = own lane) ----
    {
        uint4 pk[4];
#pragma unroll
        for (int q4 = 0; q4 < 4; ++q4) {
            unsigned a0 = (unsigned)f2bf(hid[8 * q4 + 0]) | ((unsigned)f2bf(hid[8 * q4 + 1]) << 16);
            unsigned a1 = (unsigned)f2bf(hid[8 * q4 + 2]) | ((unsigned)f2bf(hid[8 * q4 + 3]) << 16);
            unsigned a2 = (unsigned)f2bf(hid[8 * q4 + 4]) | ((unsigned)f2bf(hid[8 * q4 + 5]) << 16);
            unsigned a3 = (unsigned)f2bf(hid[8 * q4 + 6]) | ((unsigned)f2bf(hid[8 * q4 + 7]) << 16);
            pk[q4] = make_uint4(a0, a1, a2, a3);
        }
#pragma unroll
        for (int q4 = 0; q4 < 4; ++q4) hidp[wv][lane][q4] = pk[q4];
    }
    // same-wave LDS write->read: compiler inserts the lgkmcnt hazard waits

    const f32x4 zero = {0.f, 0.f, 0.f, 0.f};
#pragma unroll
    for (int m = 0; m < 4; ++m) {
        const uint4 av = hidp[wv][m * 16 + cl][lane >> 4];
        const bf16x8 afr = __builtin_bit_cast(bf16x8, av);
        const f32x4 d0 = __builtin_amdgcn_mfma_f32_16x16x32_bf16(afr, bfr[0], zero, 0, 0, 0);
        const f32x4 d1 = __builtin_amdgcn_mfma_f32_16x16x32_bf16(afr, bfr[1], zero, 0, 0, 0);
        float m0 = fmaxf(fmaxf(d0[0], d0[1]), fmaxf(d0[2], d0[3]));
        float m1 = fmaxf(fmaxf(d1[0], d1[1]), fmaxf(d1[2], d1[3]));
        m0 = fmaxf(m0, fxor<16>(m0));  m1 = fmaxf(m1, fxor<16>(m1));
        m0 = fmaxf(m0, fxor<32>(m0));  m1 = fmaxf(m1, fxor<32>(m1));
        const int bp = wv * 4 + m;
        hs[bp][cl]      = fmaxf(bb[cl]      + m0, 0.0f);   // outer relu
        hs[bp][16 + cl] = fmaxf(bb[16 + cl] + m1, 0.0f);
    }
    __syncthreads();

    if constexpr (MODE == 1) {
        // pre2: thread (pl,k) computes channels k and k+16 of w2,v2
        float accA = bna[k], accB = bna[16 + k];
#pragma unroll
        for (int c = 0; c < 32; ++c) {
            const float hc = hs[pl][c];
            accA = fmaf(hc, Wna[c * 32 + k],      accA);
            accB = fmaf(hc, Wna[c * 32 + 16 + k], accB);
        }
        float vA = 0.f, vB = 0.f;
#pragma unroll
        for (int d = 0; d < 3; ++d) {
            const float pd = pos[3 * (size_t)p + d];
            vA = fmaf(pd, Wna[(32 + d) * 32 + k],      vA);
            vB = fmaf(pd, Wna[(32 + d) * 32 + 16 + k], vB);
        }
        outA[(size_t)p * 32 + k]      = accA + vA;
        outA[(size_t)p * 32 + 16 + k] = accB + vB;
        outB[(size_t)p * 32 + k]      = vA;
        outB[(size_t)p * 32 + 16 + k] = vB;
    } else {
        // fused pool: block-local max over 16 points, then device atomicMax
        if (tid < 32) {
            float m = hs[0][tid];
#pragma unroll
            for (int p2 = 1; p2 < 16; ++p2) m = fmaxf(m, hs[p2][tid]);
            atomicMax((int*)&gbuf[cloud * 32 + tid], __float_as_int(m));
        }
        __syncthreads();
        if (tid == 0) {
            __threadfence();
            lastFlag = (atomicAdd(counter, 1) == (int)gridDim.x - 1);
        }
        __syncthreads();
        if (lastFlag) {
            for (int t = tid; t < NCLOUDS * 32; t += 256)
                gl[t] = __int_as_float(atomicMax((int*)&gbuf[t], 0)); // coherent read
            __syncthreads();
            if (tid < NCLOUDS * 10) {
                const int cl2 = tid / 10, cls = tid - cl2 * 10;
                float s2 = bc[cls];
#pragma unroll
                for (int c = 0; c < 32; ++c)
                    s2 = fmaf(gl[cl2 * 32 + c], Wc[c * 10 + cls], s2);
                out[tid] = s2;
            }
        }
    }
}

extern "C" void kernel_launch(void* const* d_in, const int* in_sizes, int n_in,
                              void* d_out, int out_size, void* d_ws, size_t ws_size,
                              hipStream_t stream)
{
    const float* pos = (const float*)d_in[0];
    const float* W1a = (const float*)d_in[2];
    const float* b1a = (const float*)d_in[3];
    const float* W1b = (const float*)d_in[4];
    const float* b1b = (const float*)d_in[5];
    const float* W2a = (const float*)d_in[6];
    const float* b2a = (const float*)d_in[7];
    const float* W2b = (const float*)d_in[8];
    const float* b2b = (const float*)d_in[9];
    const float* Wc  = (const float*)d_in[10];
    const float* bc  = (const float*)d_in[11];

    int*   knn     = (int*)d_ws;                                   // 2 MB
    float* w1      = (float*)((char*)d_ws + (size_t)(2  << 20));   // 4 MB
    float* v1      = (float*)((char*)d_ws + (size_t)(6  << 20));   // 4 MB
    float* w2      = (float*)((char*)d_ws + (size_t)(10 << 20));   // 4 MB
    float* v2      = (float*)((char*)d_ws + (size_t)(14 << 20));   // 4 MB
    float* gbuf    = (float*)((char*)d_ws + (size_t)(18 << 20));   // 2 KB
    int*   counter = (int*)((char*)d_ws + (size_t)(18 << 20) + 4096);
    float* out     = (float*)d_out;

    const int npts = NCLOUDS * N_PER;

    knn_kernel<<<dim3(NCLOUDS * 64), dim3(512), 0, stream>>>(
        pos, knn, W1a, b1a, w1, v1, gbuf, counter);
    layer_kernel<1><<<dim3(npts * KNN_K / 256), dim3(256), 0, stream>>>(
        knn, W1b, b1b, w1, v1, pos, W2a, b2a, w2, v2,
        nullptr, nullptr, nullptr, nullptr, nullptr);
    layer_kernel<2><<<dim3(npts * KNN_K / 256), dim3(256), 0, stream>>>(
        knn, W2b, b2b, w2, v2, pos, nullptr, nullptr, nullptr, nullptr,
        Wc, bc, gbuf, counter, out);
}